// Round 11
// baseline (637.682 us; speedup 1.0000x reference)
//
#include <hip/hip_runtime.h>
#include <hip/hip_bf16.h>

typedef __attribute__((ext_vector_type(8))) short short8;
typedef __attribute__((ext_vector_type(4))) float f32x4;

#define AS1 __attribute__((address_space(1)))
#define AS3 __attribute__((address_space(3)))

static __device__ __forceinline__ short f2bf(float f) {
    __hip_bfloat16 h = __float2bfloat16(f);
    union { __hip_bfloat16 h; short s; } u;
    u.h = h;
    return u.s;
}

// ---------------- prepack kernels ----------------

__global__ __launch_bounds__(256) void prepack_w_kernel(const int* __restrict__ wq,
                                                        const float* __restrict__ scales,
                                                        short* __restrict__ Wb,
                                                        long total8) {
    long i = (long)blockIdx.x * 256 + threadIdx.x;
    if (i >= total8) return;
    const int4* p = (const int4*)wq + i * 2;
    int4 q0 = p[0], q1 = p[1];
    float s = scales[(i * 8) >> 5];
    short8 v;
    v[0] = f2bf((float)(q0.x - 128) * s);
    v[1] = f2bf((float)(q0.y - 128) * s);
    v[2] = f2bf((float)(q0.z - 128) * s);
    v[3] = f2bf((float)(q0.w - 128) * s);
    v[4] = f2bf((float)(q1.x - 128) * s);
    v[5] = f2bf((float)(q1.y - 128) * s);
    v[6] = f2bf((float)(q1.z - 128) * s);
    v[7] = f2bf((float)(q1.w - 128) * s);
    ((short8*)Wb)[i] = v;
}

__global__ __launch_bounds__(256) void prepack_x_kernel(const float* __restrict__ x,
                                                        short* __restrict__ Xb,
                                                        long total8) {
    long i = (long)blockIdx.x * 256 + threadIdx.x;
    if (i >= total8) return;
    const float4* p = (const float4*)x + i * 2;
    float4 f0 = p[0], f1 = p[1];
    short8 v;
    v[0] = f2bf(f0.x); v[1] = f2bf(f0.y); v[2] = f2bf(f0.z); v[3] = f2bf(f0.w);
    v[4] = f2bf(f1.x); v[5] = f2bf(f1.y); v[6] = f2bf(f1.z); v[7] = f2bf(f1.w);
    ((short8*)Xb)[i] = v;
}

// ---------------- 256x256 GEMM: 16x16x32, ONE barrier per K-tile ----------------
// 512 thr = 8 waves (2M x 4N), per-wave C = 128x64 (8 m x 4 n frags), BK=64.
// LDS: A/B each [par*2+half][128x64 bf16], granule(16B) XOR swizzle (0-conflict,
// proven R5/R10). Staging is ONE tile ahead: A(t+1),B(t+1) -> par^1, issued at the
// top of tile t. WAR-safe with no mid-tile barrier: par^1's previous tenant (tile
// t-1) was fully consumed before the (t-1 -> t) boundary barrier (each wave's
// lgkm(0) precedes its arrival there). Loads get a full tile (~4000 cyc) to land,
// so the boundary VMC(0) is cheap. Within a tile only per-wave counted lgkm waits
// -> the 2 waves/SIMD slip, overlapping LDS drain with MFMA.
__global__ __launch_bounds__(512, 2)
void gemm256_kernel(const float* __restrict__ bias,
                    const short* __restrict__ Xb, const short* __restrict__ Wb,
                    float* __restrict__ out, int M, int N, int K) {
    __shared__ alignas(16) short As[4 * 8192];
    __shared__ alignas(16) short Bs[4 * 8192];

    const int nM = M >> 8, nN = N >> 8;
    int bid = blockIdx.x;
    {
        int nwg = nM * nN;
        if ((nwg & 7) == 0) bid = (bid & 7) * (nwg >> 3) + (bid >> 3);  // XCD swizzle
    }
    int pm, pn;
    {
        const int G = 8;
        if ((nN % G) == 0) {
            int per = nM * G;
            int grp = bid / per, in = bid % per;
            pn = grp * G + (in % G);
            pm = in / G;
        } else { pn = bid % nN; pm = bid / nN; }
    }

    const int tid  = threadIdx.x;
    const int lane = tid & 63;
    const int wid  = tid >> 6;
    const int wm   = wid >> 2;     // 0..1
    const int wn   = wid & 3;      // 0..3
    const int q4   = lane >> 4;
    const int l15  = lane & 15;
    const int lx   = lane & 7;

    const long bm = (long)pm << 8, bn = (long)pn << 8;
    const long Kl = K;
    const int  NT = K >> 6;

    // per-parity read bases (shorts); R5/R10's conflict-free pattern
    const int rA0 = wm * 8192 + l15 * 64;
    const int rA1 = (2 + wm) * 8192 + l15 * 64;
    const int rB0 = (wn >> 1) * 8192 + ((wn & 1) * 64 + l15) * 64;
    const int rB1 = rB0 + 2 * 8192;
    const int sg0 = (q4 ^ lx) * 8;        // k-step 0 granule (swizzled)
    const int sg1 = ((4 + q4) ^ lx) * 8;  // k-step 1

    // staging geometry (identical to R5/R10)
    const int chnk    = wid * 1024;
    const int srowrel = wid * 16 + (lane >> 3);
    const int scol    = ((lane & 7) ^ (lane >> 3)) * 8;

    const short* aS00 = Xb + (bm + 0   + srowrel + 0) * Kl + scol;
    const short* aS01 = Xb + (bm + 0   + srowrel + 8) * Kl + scol;
    const short* aS10 = Xb + (bm + 128 + srowrel + 0) * Kl + scol;
    const short* aS11 = Xb + (bm + 128 + srowrel + 8) * Kl + scol;
    const short* bS00 = Wb + (bn + 0   + srowrel + 0) * Kl + scol;
    const short* bS01 = Wb + (bn + 0   + srowrel + 8) * Kl + scol;
    const short* bS10 = Wb + (bn + 128 + srowrel + 0) * Kl + scol;
    const short* bS11 = Wb + (bn + 128 + srowrel + 8) * Kl + scol;

#define STGA(H, PARL, OFF) {                                                          \
    __builtin_amdgcn_global_load_lds((const AS1 void*)(aS##H##0 + (OFF)),             \
        (AS3 void*)&As[((PARL) * 2 + (H)) * 8192 + chnk], 16, 0, 0);                  \
    __builtin_amdgcn_global_load_lds((const AS1 void*)(aS##H##1 + (OFF)),             \
        (AS3 void*)&As[((PARL) * 2 + (H)) * 8192 + chnk + 512], 16, 0, 0); }
#define STGB(H, PARL, OFF) {                                                          \
    __builtin_amdgcn_global_load_lds((const AS1 void*)(bS##H##0 + (OFF)),             \
        (AS3 void*)&Bs[((PARL) * 2 + (H)) * 8192 + chnk], 16, 0, 0);                  \
    __builtin_amdgcn_global_load_lds((const AS1 void*)(bS##H##1 + (OFF)),             \
        (AS3 void*)&Bs[((PARL) * 2 + (H)) * 8192 + chnk + 512], 16, 0, 0); }

// all 8 A m-frags for one k-step (single buffer, reused per k-step)
#define RDA8(RA, SG) {                                                                \
    ak[0] = *(const short8*)&As[(RA) + 0 * 1024 + (SG)];                              \
    ak[1] = *(const short8*)&As[(RA) + 1 * 1024 + (SG)];                              \
    ak[2] = *(const short8*)&As[(RA) + 2 * 1024 + (SG)];                              \
    ak[3] = *(const short8*)&As[(RA) + 3 * 1024 + (SG)];                              \
    ak[4] = *(const short8*)&As[(RA) + 4 * 1024 + (SG)];                              \
    ak[5] = *(const short8*)&As[(RA) + 5 * 1024 + (SG)];                              \
    ak[6] = *(const short8*)&As[(RA) + 6 * 1024 + (SG)];                              \
    ak[7] = *(const short8*)&As[(RA) + 7 * 1024 + (SG)]; }

// all 8 B frags (4 n x 2 k-steps)
#define LDB8(RB) { _Pragma("unroll") for (int n = 0; n < 4; ++n) {                    \
    bfr[n][0] = *(const short8*)&Bs[(RB) + n * 1024 + sg0];                           \
    bfr[n][1] = *(const short8*)&Bs[(RB) + n * 1024 + sg1]; } }

#define MFMA32(KK) { __builtin_amdgcn_s_setprio(1);                                   \
    _Pragma("unroll") for (int mi = 0; mi < 8; ++mi)                                  \
        _Pragma("unroll") for (int n = 0; n < 4; ++n)                                 \
            acc[mi][n] = __builtin_amdgcn_mfma_f32_16x16x32_bf16(                     \
                ak[mi], bfr[n][KK], acc[mi][n], 0, 0, 0);                             \
    __builtin_amdgcn_s_setprio(0); }

#define BAR  __builtin_amdgcn_s_barrier()
#define WLGN(n) { asm volatile("s_waitcnt lgkmcnt(" #n ")" ::: "memory");             \
                  __builtin_amdgcn_sched_barrier(0); }
#define VMC(n)  asm volatile("s_waitcnt vmcnt(" #n ")" ::: "memory")

// One K-tile: stage (t+1) -> PARN at top, then reads + MFMA with per-wave waits
// only; single boundary {vmcnt(0); barrier} at the end.
#define TILE1(RA, RB, PARN, OFFN, DO_S, LAST) {                                       \
    if (DO_S) { STGA(0, PARN, OFFN); STGA(1, PARN, OFFN);                             \
                STGB(0, PARN, OFFN); STGB(1, PARN, OFFN); }                           \
    LDB8(RB);                                                                         \
    RDA8(RA, sg0);                                                                    \
    WLGN(0);                                                                          \
    MFMA32(0);                                                                        \
    RDA8(RA, sg1);                                                                    \
    WLGN(0);                                                                          \
    MFMA32(1);                                                                        \
    if (!(LAST)) { VMC(0); BAR; } }

    f32x4 acc[8][4];
#pragma unroll
    for (int m = 0; m < 8; ++m)
#pragma unroll
        for (int n = 0; n < 4; ++n) acc[m][n] = (f32x4){0.f, 0.f, 0.f, 0.f};

    short8 ak[8], bfr[4][2];

    // ---- prologue: stage tile 0 -> par0 only ----
    STGA(0, 0, 0); STGA(1, 0, 0);
    STGB(0, 0, 0); STGB(1, 0, 0);
    VMC(0);
    BAR;

    // ---- main loop: tile t stages t+1; pairs (par0, par1) ----
    for (int t = 0; t < NT - 2; t += 2) {
        const long o1 = ((long)t + 1) << 6;
        const long o2 = o1 + 64;
        TILE1(rA0, rB0, 1, o1, true, false);
        TILE1(rA1, rB1, 0, o2, true, false);
    }
    // ---- final pair: (NT-2) stages (NT-1); (NT-1) stages nothing ----
    {
        const long o1 = ((long)NT - 1) << 6;
        TILE1(rA0, rB0, 1, o1, true, false);
        TILE1(rA1, rB1, 0, 0, false, true);
    }

    // ---- epilogue: C/D layout col = lane&15, row = (lane>>4)*4 + reg ----
#pragma unroll
    for (int n = 0; n < 4; ++n) {
        long col = bn + wn * 64 + n * 16 + l15;
        float bv = bias[col];
#pragma unroll
        for (int m = 0; m < 8; ++m) {
            long row = bm + wm * 128 + m * 16 + q4 * 4;
#pragma unroll
            for (int r = 0; r < 4; ++r)
                out[(row + r) * (long)N + col] = acc[m][n][r] + bv;
        }
    }
#undef STGA
#undef STGB
#undef RDA8
#undef LDB8
#undef MFMA32
#undef BAR
#undef WLGN
#undef VMC
#undef TILE1
}

// ---------------- fallback 128x128 GEMM (handles fused / odd shapes) ----------------

template <bool PRE_A, bool PRE_B>
__global__ __launch_bounds__(256, 2)
void gemm_kernel(const float* __restrict__ x, const int* __restrict__ wq,
                 const float* __restrict__ scales, const float* __restrict__ bias,
                 const short* __restrict__ Xb, const short* __restrict__ Wb,
                 float* __restrict__ out, int M, int N, int K) {
    constexpr int BM = 128, BN = 128, BK = 64;
    __shared__ alignas(16) short As[BM * BK];
    __shared__ alignas(16) short Bs[BN * BK];

    const int nM = M / BM, nN = N / BN;
    int bid = blockIdx.x;
    int pm, pn;
    const int G = 8;
    if ((nN % G) == 0) {
        int per = nM * G;
        int grp = bid / per;
        int in  = bid % per;
        pn = grp * G + (in % G);
        pm = in / G;
    } else {
        pn = bid % nN;
        pm = bid / nN;
    }

    const int tid  = threadIdx.x;
    const int lane = tid & 63;
    const int wv   = tid >> 6;
    const int wm   = (wv >> 1) * 64;
    const int wn   = (wv & 1) * 64;
    const int q    = lane >> 4;
    const int l15  = lane & 15;
    const int sxor = lane & 7;

    const long bm = (long)pm * BM, bn = (long)pn * BN;

    f32x4 acc[4][4];
#pragma unroll
    for (int i = 0; i < 4; ++i)
#pragma unroll
        for (int j = 0; j < 4; ++j) acc[i][j] = (f32x4){0.f, 0.f, 0.f, 0.f};

    const int srow = tid >> 3;
    const int scg  = tid & 7;

    const int sg0   = q ^ sxor;
    const int aOff0 = (wm + l15) * 64 + sg0 * 8;
    const int aOff1 = (wm + l15) * 64 + (sg0 ^ 4) * 8;
    const int bOff0 = (wn + l15) * 64 + sg0 * 8;
    const int bOff1 = (wn + l15) * 64 + (sg0 ^ 4) * 8;

    const int prRow  = lane >> 3;
    const int prGsrc = (lane & 7) ^ (lane >> 3);

    for (int k0 = 0; k0 < K; k0 += BK) {
        if constexpr (PRE_A) {
#pragma unroll
            for (int i = 0; i < 4; ++i) {
                int r = wv * 32 + i * 8 + prRow;
                const short* src = Xb + (bm + r) * (long)K + k0 + prGsrc * 8;
                __builtin_amdgcn_global_load_lds((const AS1 void*)src,
                                                 (AS3 void*)&As[(wv * 32 + i * 8) * 64],
                                                 16, 0, 0);
            }
        } else {
#pragma unroll
            for (int i = 0; i < 4; ++i) {
                int r = i * 32 + srow;
                const float4* p = (const float4*)(x + (bm + r) * (long)K + k0 + scg * 8);
                float4 f0 = p[0], f1 = p[1];
                short8 v;
                v[0] = f2bf(f0.x); v[1] = f2bf(f0.y); v[2] = f2bf(f0.z); v[3] = f2bf(f0.w);
                v[4] = f2bf(f1.x); v[5] = f2bf(f1.y); v[6] = f2bf(f1.z); v[7] = f2bf(f1.w);
                int sg = scg ^ (r & 7);
                *(short8*)&As[r * 64 + sg * 8] = v;
            }
        }
        if constexpr (PRE_B) {
#pragma unroll
            for (int i = 0; i < 4; ++i) {
                int r = wv * 32 + i * 8 + prRow;
                const short* src = Wb + (bn + r) * (long)K + k0 + prGsrc * 8;
                __builtin_amdgcn_global_load_lds((const AS1 void*)src,
                                                 (AS3 void*)&Bs[(wv * 32 + i * 8) * 64],
                                                 16, 0, 0);
            }
        } else {
#pragma unroll
            for (int i = 0; i < 4; ++i) {
                int r = i * 32 + srow;
                const int4* p = (const int4*)(wq + (bn + r) * (long)K + k0 + scg * 8);
                int4 q0 = p[0], q1 = p[1];
                float s = scales[(bn + r) * (long)(K >> 5) + ((k0 + scg * 8) >> 5)];
                short8 v;
                v[0] = f2bf((float)(q0.x - 128) * s);
                v[1] = f2bf((float)(q0.y - 128) * s);
                v[2] = f2bf((float)(q0.z - 128) * s);
                v[3] = f2bf((float)(q0.w - 128) * s);
                v[4] = f2bf((float)(q1.x - 128) * s);
                v[5] = f2bf((float)(q1.y - 128) * s);
                v[6] = f2bf((float)(q1.z - 128) * s);
                v[7] = f2bf((float)(q1.w - 128) * s);
                int sg = scg ^ (r & 7);
                *(short8*)&Bs[r * 64 + sg * 8] = v;
            }
        }
        __syncthreads();

#pragma unroll
        for (int kk = 0; kk < 2; ++kk) {
            short8 a[4], b[4];
            const int aBase = kk ? aOff1 : aOff0;
            const int bBase = kk ? bOff1 : bOff0;
#pragma unroll
            for (int mi = 0; mi < 4; ++mi) a[mi] = *(const short8*)&As[aBase + mi * 16 * 64];
#pragma unroll
            for (int nj = 0; nj < 4; ++nj) b[nj] = *(const short8*)&Bs[bBase + nj * 16 * 64];
#pragma unroll
            for (int mi = 0; mi < 4; ++mi)
#pragma unroll
                for (int nj = 0; nj < 4; ++nj)
                    acc[mi][nj] = __builtin_amdgcn_mfma_f32_16x16x32_bf16(
                        a[mi], b[nj], acc[mi][nj], 0, 0, 0);
        }
        __syncthreads();
    }

#pragma unroll
    for (int nj = 0; nj < 4; ++nj) {
        long col = bn + wn + nj * 16 + l15;
        float bv = bias[col];
#pragma unroll
        for (int mi = 0; mi < 4; ++mi) {
            long row = bm + wm + mi * 16 + q * 4;
#pragma unroll
            for (int r2 = 0; r2 < 4; ++r2)
                out[(row + r2) * (long)N + col] = acc[mi][nj][r2] + bv;
        }
    }
}

// ---------------- launch ----------------

extern "C" void kernel_launch(void* const* d_in, const int* in_sizes, int n_in,
                              void* d_out, int out_size, void* d_ws, size_t ws_size,
                              hipStream_t stream) {
    const float* x      = (const float*)d_in[0];
    const int*   wq     = (const int*)d_in[1];
    const float* scales = (const float*)d_in[2];
    const float* bias   = (const float*)d_in[3];
    float*       out    = (float*)d_out;

    const long N = (long)in_sizes[3];
    const long K = (long)in_sizes[1] / N;
    const long M = (long)in_sizes[0] / K;

    const size_t needW = (size_t)N * K * sizeof(short);
    const size_t needX = (size_t)M * K * sizeof(short);

    short* Wb = (short*)d_ws;
    short* Xb = Wb + (size_t)N * K;

    const bool preB = (d_ws != nullptr) && ws_size >= needW;
    const bool preA = preB && ws_size >= (needW + needX);

    if (preB) {
        long t8 = N * K / 8;
        prepack_w_kernel<<<dim3((unsigned)((t8 + 255) / 256)), dim3(256), 0, stream>>>(
            wq, scales, Wb, t8);
    }
    if (preA) {
        long t8 = M * K / 8;
        prepack_x_kernel<<<dim3((unsigned)((t8 + 255) / 256)), dim3(256), 0, stream>>>(
            x, Xb, t8);
    }

    const long NTl = K / 64;
    const bool big = preA && (M % 256 == 0) && (N % 256 == 0) && (K % 64 == 0) &&
                     (NTl >= 4) && (NTl % 2 == 0);

    if (big) {
        dim3 grid((unsigned)((M / 256) * (N / 256))), block(512);
        gemm256_kernel<<<grid, block, 0, stream>>>(bias, Xb, Wb, out, (int)M, (int)N, (int)K);
    } else {
        dim3 grid((unsigned)((M / 128) * (N / 128))), block(256);
        if (preA)
            gemm_kernel<true, true><<<grid, block, 0, stream>>>(x, wq, scales, bias, Xb, Wb,
                                                                out, (int)M, (int)N, (int)K);
        else if (preB)
            gemm_kernel<false, true><<<grid, block, 0, stream>>>(x, wq, scales, bias, Xb, Wb,
                                                                 out, (int)M, (int)N, (int)K);
        else
            gemm_kernel<false, false><<<grid, block, 0, stream>>>(x, wq, scales, bias, Xb, Wb,
                                                                  out, (int)M, (int)N, (int)K);
    }
}